// Round 5
// baseline (1195.959 us; speedup 1.0000x reference)
//
#include <hip/hip_runtime.h>
#include <math.h>

#define BN_EPS 1e-5f

namespace {

constexpr int Bb = 32;   // batch
constexpr int Cc = 512;  // channels
constexpr int Nn = 1024; // spatial (H*W)
constexpr int Ee = 1024; // embed

typedef __attribute__((ext_vector_type(8))) short short8;
typedef __attribute__((ext_vector_type(4))) float f32x4;
typedef __attribute__((ext_vector_type(4))) unsigned short ushort4_t;

struct bfpair { unsigned short h, l; };

__device__ __forceinline__ unsigned short bf16_rne(float v) {
  unsigned u = __builtin_bit_cast(unsigned, v);
  unsigned r = u + 0x7FFFu + ((u >> 16) & 1u);
  return (unsigned short)(r >> 16);
}
__device__ __forceinline__ float bf16_to_f(unsigned short h) {
  unsigned u = ((unsigned)h) << 16;
  return __builtin_bit_cast(float, u);
}
__device__ __forceinline__ bfpair split_bf(float v) {
  bfpair p;
  p.h = bf16_rne(v);
  p.l = bf16_rne(v - bf16_to_f(p.h));
  return p;
}

__device__ __forceinline__ void gll16(const void* g, void* l) {
  __builtin_amdgcn_global_load_lds(
      (const __attribute__((address_space(1))) void*)g,
      (__attribute__((address_space(3))) void*)l, 16, 0, 0);
}

__global__ __launch_bounds__(256) void prep_st_kernel(
    const float* __restrict__ g, const float* __restrict__ be,
    const float* __restrict__ mn, const float* __restrict__ vr,
    float* __restrict__ s, float* __restrict__ t, int n) {
  int i = blockIdx.x * blockDim.x + threadIdx.x;
  if (i < n) {
    float inv = rsqrtf(vr[i] + BN_EPS);
    float sc = g[i] * inv;
    s[i] = sc;
    t[i] = be[i] - mn[i] * sc;
  }
}

// One x pass -> all three BN+ReLU projections, split hi/lo bf16.
__global__ __launch_bounds__(256) void convert_y3(
    const float* __restrict__ x,
    const float* __restrict__ sq, const float* __restrict__ tq,
    const float* __restrict__ sk, const float* __restrict__ tk,
    const float* __restrict__ sv, const float* __restrict__ tv,
    unsigned short* __restrict__ yqh, unsigned short* __restrict__ yql,
    unsigned short* __restrict__ ykh, unsigned short* __restrict__ ykl,
    unsigned short* __restrict__ yvh, unsigned short* __restrict__ yvl,
    long total4) {
  for (long i = (long)blockIdx.x * 256 + threadIdx.x; i < total4; i += (long)gridDim.x * 256) {
    float4 v = ((const float4*)x)[i];
    int n4 = (int)(i & 255);  // N/4 = 256 float4 per row
    float4 a, b;
    ushort4_t hv, lv;
    // q
    a = ((const float4*)sq)[n4]; b = ((const float4*)tq)[n4];
    {
      bfpair p0 = split_bf(fmaxf(fmaf(v.x, a.x, b.x), 0.f));
      bfpair p1 = split_bf(fmaxf(fmaf(v.y, a.y, b.y), 0.f));
      bfpair p2 = split_bf(fmaxf(fmaf(v.z, a.z, b.z), 0.f));
      bfpair p3 = split_bf(fmaxf(fmaf(v.w, a.w, b.w), 0.f));
      hv.x = p0.h; hv.y = p1.h; hv.z = p2.h; hv.w = p3.h;
      lv.x = p0.l; lv.y = p1.l; lv.z = p2.l; lv.w = p3.l;
      *(ushort4_t*)&yqh[i * 4] = hv; *(ushort4_t*)&yql[i * 4] = lv;
    }
    // k
    a = ((const float4*)sk)[n4]; b = ((const float4*)tk)[n4];
    {
      bfpair p0 = split_bf(fmaxf(fmaf(v.x, a.x, b.x), 0.f));
      bfpair p1 = split_bf(fmaxf(fmaf(v.y, a.y, b.y), 0.f));
      bfpair p2 = split_bf(fmaxf(fmaf(v.z, a.z, b.z), 0.f));
      bfpair p3 = split_bf(fmaxf(fmaf(v.w, a.w, b.w), 0.f));
      hv.x = p0.h; hv.y = p1.h; hv.z = p2.h; hv.w = p3.h;
      lv.x = p0.l; lv.y = p1.l; lv.z = p2.l; lv.w = p3.l;
      *(ushort4_t*)&ykh[i * 4] = hv; *(ushort4_t*)&ykl[i * 4] = lv;
    }
    // v
    a = ((const float4*)sv)[n4]; b = ((const float4*)tv)[n4];
    {
      bfpair p0 = split_bf(fmaxf(fmaf(v.x, a.x, b.x), 0.f));
      bfpair p1 = split_bf(fmaxf(fmaf(v.y, a.y, b.y), 0.f));
      bfpair p2 = split_bf(fmaxf(fmaf(v.z, a.z, b.z), 0.f));
      bfpair p3 = split_bf(fmaxf(fmaf(v.w, a.w, b.w), 0.f));
      hv.x = p0.h; hv.y = p1.h; hv.z = p2.h; hv.w = p3.h;
      lv.x = p0.l; lv.y = p1.l; lv.z = p2.l; lv.w = p3.l;
      *(ushort4_t*)&yvh[i * 4] = hv; *(ushort4_t*)&yvl[i * 4] = lv;
    }
  }
}

// plain f32 -> hi/lo bf16 split (weights)
__global__ __launch_bounds__(256) void convert_w(
    const float* __restrict__ wsrc, unsigned short* __restrict__ wh,
    unsigned short* __restrict__ wl, long total4) {
  for (long i = (long)blockIdx.x * 256 + threadIdx.x; i < total4; i += (long)gridDim.x * 256) {
    float4 v = ((const float4*)wsrc)[i];
    bfpair p0 = split_bf(v.x), p1 = split_bf(v.y), p2 = split_bf(v.z), p3 = split_bf(v.w);
    ushort4_t hv, lv;
    hv.x = p0.h; hv.y = p1.h; hv.z = p2.h; hv.w = p3.h;
    lv.x = p0.l; lv.y = p1.l; lv.z = p2.l; lv.w = p3.l;
    *(ushort4_t*)&wh[i * 4] = hv;
    *(ushort4_t*)&wl[i * 4] = lv;
  }
}

// Split-bf16 NT GEMM: C[m][n] = alpha * sum_k A[m][k]*B[n][k], A=Ah+Al, B=Bh+Bl.
// 128x128 tile, BK=32, 256 threads (4 waves, 2x2 of 64x64), mfma 16x16x32 bf16.
// acc += Ah*Bh + Ah*Bl + Al*Bh  (Al*Bl dropped, O(eps^2)).
// LDS chunk-XOR swizzle: LDS[row][chunk] holds global chunk (chunk ^ ((row>>1)&3));
// write side via permuted global src col (gll16 dest stays linear), read side via
// permuted ds_read col. Makes 16-lane fragment reads 2-way (free) instead of 8-way.
// 1-D grid with XCD-chunked swizzle; logical order: x fastest, z slowest.
template<bool SPLIT>
__global__ __launch_bounds__(256) void gemm3(
    const unsigned short* __restrict__ Ah, const unsigned short* __restrict__ Al,
    long ldA, long bsA,
    const unsigned short* __restrict__ Bh, const unsigned short* __restrict__ Bl,
    long ldB, long bsB,
    float* __restrict__ Cf, unsigned short* __restrict__ Chi, unsigned short* __restrict__ Clo,
    long ldC, long bsC, int K, float alpha, int gx, int gy) {
  __shared__ unsigned short sAh[128][32], sAl[128][32], sBh[128][32], sBl[128][32];

  const int nb = gridDim.x;
  int f = blockIdx.x;
  if ((nb & 7) == 0) f = (f & 7) * (nb >> 3) + (f >> 3);  // XCD-chunked swizzle (bijective, nb%8==0)
  const int n0 = (f % gx) * 128;
  const int m0 = ((f / gx) % gy) * 128;
  const long zb = f / (gx * gy);

  const int t = threadIdx.x, lane = t & 63, w = t >> 6;

  const int sr = lane >> 2;                                   // staging row within 16-row group
  const int sk = (((lane & 3) ^ ((lane >> 3) & 3)) * 8);      // swizzled staging col (elements)
  const int wr = w >> 1, wc = w & 1;                          // wave quadrant
  const int fr = lane & 15;                                   // fragment row/col
  const int kq = ((((lane >> 4) & 3) ^ ((fr >> 1) & 3)) * 8); // swizzled fragment col (elements)

  const unsigned short* a0 = Ah + zb * bsA + (long)(m0 + w * 32 + sr) * ldA + sk;
  const unsigned short* a1 = Al + zb * bsA + (long)(m0 + w * 32 + sr) * ldA + sk;
  const unsigned short* b0 = Bh + zb * bsB + (long)(n0 + w * 32 + sr) * ldB + sk;
  const unsigned short* b1 = Bl + zb * bsB + (long)(n0 + w * 32 + sr) * ldB + sk;
  const long a16 = 16 * ldA, b16 = 16 * ldB;

  f32x4 acc[4][4] = {};

  for (int k0 = 0; k0 < K; k0 += 32) {
    __syncthreads();  // previous tile fully consumed
    gll16(a0, &sAh[w * 32][0]);      gll16(a0 + a16, &sAh[w * 32 + 16][0]);
    gll16(a1, &sAl[w * 32][0]);      gll16(a1 + a16, &sAl[w * 32 + 16][0]);
    gll16(b0, &sBh[w * 32][0]);      gll16(b0 + b16, &sBh[w * 32 + 16][0]);
    gll16(b1, &sBl[w * 32][0]);      gll16(b1 + b16, &sBl[w * 32 + 16][0]);
    a0 += 32; a1 += 32; b0 += 32; b1 += 32;
    __syncthreads();  // staged data visible (compiler drains vmcnt before barrier)

    short8 ah[4], al[4], bh[4], bl[4];
#pragma unroll
    for (int i = 0; i < 4; ++i) {
      ah[i] = *(const short8*)&sAh[wr * 64 + i * 16 + fr][kq];
      al[i] = *(const short8*)&sAl[wr * 64 + i * 16 + fr][kq];
      bh[i] = *(const short8*)&sBh[wc * 64 + i * 16 + fr][kq];
      bl[i] = *(const short8*)&sBl[wc * 64 + i * 16 + fr][kq];
    }
#pragma unroll
    for (int i = 0; i < 4; ++i)
#pragma unroll
      for (int j = 0; j < 4; ++j) {
        acc[i][j] = __builtin_amdgcn_mfma_f32_16x16x32_bf16(ah[i], bh[j], acc[i][j], 0, 0, 0);
        acc[i][j] = __builtin_amdgcn_mfma_f32_16x16x32_bf16(ah[i], bl[j], acc[i][j], 0, 0, 0);
        acc[i][j] = __builtin_amdgcn_mfma_f32_16x16x32_bf16(al[i], bh[j], acc[i][j], 0, 0, 0);
      }
  }

  // epilogue: C/D layout col = lane&15, row = (lane>>4)*4 + reg  [verified m89/m91]
  const int rb = ((lane >> 4) & 3) * 4;
#pragma unroll
  for (int i = 0; i < 4; ++i)
#pragma unroll
    for (int j = 0; j < 4; ++j) {
      long col = n0 + wc * 64 + j * 16 + fr;
#pragma unroll
      for (int v = 0; v < 4; ++v) {
        long row = m0 + wr * 64 + i * 16 + rb + v;
        float val = acc[i][j][v] * alpha;
        long idx = zb * bsC + row * ldC + col;
        if (SPLIT) {
          bfpair p = split_bf(val);
          Chi[idx] = p.h;
          Clo[idx] = p.l;
        } else {
          Cf[idx] = val;
        }
      }
    }
}

// softmax over rows of 1024 f32, writes P split as hi[1024]|lo[1024] ushorts in place.
__global__ __launch_bounds__(256) void softmax_rows(float* __restrict__ S) {
  long row = blockIdx.x;
  float* p = S + row * 1024;
  int t = threadIdx.x;
  float4 v = *(float4*)(p + 4 * t);
  float mx = fmaxf(fmaxf(v.x, v.y), fmaxf(v.z, v.w));
#pragma unroll
  for (int i = 1; i < 64; i <<= 1) mx = fmaxf(mx, __shfl_xor(mx, i));
  __shared__ float redm[4];
  __shared__ float reds[4];
  int wave = t >> 6, lane = t & 63;
  if (lane == 0) redm[wave] = mx;
  __syncthreads();
  mx = fmaxf(fmaxf(redm[0], redm[1]), fmaxf(redm[2], redm[3]));
  float e0 = expf(v.x - mx), e1 = expf(v.y - mx);
  float e2 = expf(v.z - mx), e3 = expf(v.w - mx);
  float sum = (e0 + e1) + (e2 + e3);
#pragma unroll
  for (int i = 1; i < 64; i <<= 1) sum += __shfl_xor(sum, i);
  if (lane == 0) reds[wave] = sum;
  __syncthreads();
  sum = (reds[0] + reds[1]) + (reds[2] + reds[3]);
  float inv = 1.0f / sum;
  bfpair p0 = split_bf(e0 * inv), p1 = split_bf(e1 * inv);
  bfpair p2 = split_bf(e2 * inv), p3 = split_bf(e3 * inv);
  ushort4_t hv, lv;
  hv.x = p0.h; hv.y = p1.h; hv.z = p2.h; hv.w = p3.h;
  lv.x = p0.l; lv.y = p1.l; lv.z = p2.l; lv.w = p3.l;
  unsigned short* ph = (unsigned short*)p;
  *(ushort4_t*)&ph[4 * t] = hv;          // hi: ushorts [0,1024)
  *(ushort4_t*)&ph[1024 + 4 * t] = lv;   // lo: ushorts [1024,2048)
}

}  // namespace

extern "C" void kernel_launch(void* const* d_in, const int* in_sizes, int n_in,
                              void* d_out, int out_size, void* d_ws, size_t ws_size,
                              hipStream_t stream) {
  const float* x  = (const float*)d_in[0];
  const float* qg = (const float*)d_in[1];
  const float* qb = (const float*)d_in[2];
  const float* qm = (const float*)d_in[3];
  const float* qv = (const float*)d_in[4];
  const float* kg = (const float*)d_in[5];
  const float* kb = (const float*)d_in[6];
  const float* km = (const float*)d_in[7];
  const float* kv = (const float*)d_in[8];
  const float* vg = (const float*)d_in[9];
  const float* vb = (const float*)d_in[10];
  const float* vm = (const float*)d_in[11];
  const float* vv = (const float*)d_in[12];
  const float* Wq = (const float*)d_in[13];
  const float* Wk = (const float*)d_in[14];
  const float* Wv = (const float*)d_in[15];
  const float* Wp = (const float*)d_in[16];

  // ---- workspace layout ----
  // header 64 KiB: BN scale/shift (6x1024 f32)
  // W hi/lo: 8 arrays of 1M ushort = 16 MiB
  // per batch: yq/yk/yv hi/lo 6 MiB, Q hi/lo 2, K hi/lo 2, Vt hi/lo 2, S f32 4 => 16 MiB
  const size_t wMB  = 16UL * 1024 * 1024;
  const size_t perB = 16UL * 1024 * 1024;
  int G = 32;
  while (G > 1 && 65536 + wMB + (size_t)G * perB > ws_size) G >>= 1;

  char* ws = (char*)d_ws;
  float* sq = (float*)ws;
  float* tq = sq + 1024;
  float* sk = tq + 1024;
  float* tk = sk + 1024;
  float* sv = tk + 1024;
  float* tv = sv + 1024;

  const long WE = 1024L * 1024;  // elements per weight matrix
  unsigned short* Wqh = (unsigned short*)(ws + 65536);
  unsigned short* Wql = Wqh + WE;
  unsigned short* Wkh = Wql + WE;
  unsigned short* Wkl = Wkh + WE;
  unsigned short* Wvh = Wkl + WE;
  unsigned short* Wvl = Wvh + WE;
  unsigned short* Wph = Wvl + WE;
  unsigned short* Wpl = Wph + WE;

  const long PB = (long)Cc * Ee;  // 524288 elements (1 MiB ushort) per batch per array
  unsigned short* yqh = Wpl + WE;
  unsigned short* yql = yqh + (long)G * PB;
  unsigned short* ykh = yql + (long)G * PB;
  unsigned short* ykl = ykh + (long)G * PB;
  unsigned short* yvh = ykl + (long)G * PB;
  unsigned short* yvl = yvh + (long)G * PB;
  unsigned short* Qh  = yvl + (long)G * PB;
  unsigned short* Ql  = Qh + (long)G * PB;
  unsigned short* Kh  = Ql + (long)G * PB;
  unsigned short* Kl  = Kh + (long)G * PB;
  unsigned short* Vth = Kl + (long)G * PB;
  unsigned short* Vtl = Vth + (long)G * PB;
  float* S = (float*)(Vtl + (long)G * PB);  // [G][E][E] f32
  unsigned short* Oth = Qh;  // reuse Q (dead after S-GEMM)
  unsigned short* Otl = Ql;

  dim3 blk(256);

  prep_st_kernel<<<dim3(4), blk, 0, stream>>>(qg, qb, qm, qv, sq, tq, Nn);
  prep_st_kernel<<<dim3(4), blk, 0, stream>>>(kg, kb, km, kv, sk, tk, Nn);
  prep_st_kernel<<<dim3(4), blk, 0, stream>>>(vg, vb, vm, vv, sv, tv, Nn);

  const long W4 = WE / 4;
  convert_w<<<dim3(1024), blk, 0, stream>>>(Wq, Wqh, Wql, W4);
  convert_w<<<dim3(1024), blk, 0, stream>>>(Wk, Wkh, Wkl, W4);
  convert_w<<<dim3(1024), blk, 0, stream>>>(Wv, Wvh, Wvl, W4);
  convert_w<<<dim3(1024), blk, 0, stream>>>(Wp, Wph, Wpl, W4);

  const long y4 = (long)G * PB / 4;

  for (int b0 = 0; b0 < Bb; b0 += G) {
    const float* xg = x + (size_t)b0 * Cc * Nn;
    float* outg = (float*)d_out + (size_t)b0 * Cc * Nn;

    // all three BN+ReLU conversions in one x pass
    convert_y3<<<dim3(2048), blk, 0, stream>>>(
        xg, sq, tq, sk, tk, sv, tv, yqh, yql, ykh, ykl, yvh, yvl, y4);

    // ---- Q = Wq x y_q: M=E, N=C, K=Nn ----
    gemm3<true><<<dim3((Cc / 128) * (Ee / 128) * G), blk, 0, stream>>>(
        Wqh, Wql, Nn, 0L, yqh, yql, Nn, PB,
        nullptr, Qh, Ql, Cc, PB, Nn, 1.0f, Cc / 128, Ee / 128);
    // ---- K ----
    gemm3<true><<<dim3((Cc / 128) * (Ee / 128) * G), blk, 0, stream>>>(
        Wkh, Wkl, Nn, 0L, ykh, ykl, Nn, PB,
        nullptr, Kh, Kl, Cc, PB, Nn, 1.0f, Cc / 128, Ee / 128);
    // ---- Vt = y_v x Wv^T: M=C, N=E, K=Nn (transposed V) ----
    gemm3<true><<<dim3((Ee / 128) * (Cc / 128) * G), blk, 0, stream>>>(
        yvh, yvl, Nn, PB, Wvh, Wvl, Nn, 0L,
        nullptr, Vth, Vtl, Ee, PB, Nn, 1.0f, Ee / 128, Cc / 128);
    // ---- S = Q K^T / 32: M=E, N=E, K=C, f32 out ----
    gemm3<false><<<dim3((Ee / 128) * (Ee / 128) * G), blk, 0, stream>>>(
        Qh, Ql, Cc, PB, Kh, Kl, Cc, PB,
        S, nullptr, nullptr, Ee, (long)Ee * Ee, Cc, 0.03125f, Ee / 128, Ee / 128);
    // ---- softmax rows -> P hi/lo packed in S ----
    softmax_rows<<<dim3(G * Ee), blk, 0, stream>>>(S);
    // ---- Ot = Vt x P^T: M=C, N=E, K=E (P rows k-contig, ld=2048) ----
    gemm3<true><<<dim3((Ee / 128) * (Cc / 128) * G), blk, 0, stream>>>(
        Vth, Vtl, Ee, PB, (unsigned short*)S, (unsigned short*)S + 1024,
        2L * Ee, 2L * Ee * Ee,
        nullptr, Oth, Otl, Ee, PB, Ee, 1.0f, Ee / 128, Cc / 128);
    // ---- out = Ot x Wp^T: M=C, N=Nn, K=E, f32 out to d_out ----
    gemm3<false><<<dim3((Nn / 128) * (Cc / 128) * G), blk, 0, stream>>>(
        Oth, Otl, Ee, PB, Wph, Wpl, Ee, 0L,
        outg, nullptr, nullptr, Nn, (long)Cc * Nn, Ee, 1.0f, Nn / 128, Cc / 128);
  }
}

// Round 6
// 853.536 us; speedup vs baseline: 1.4012x; 1.4012x over previous
//
#include <hip/hip_runtime.h>
#include <math.h>

#define BN_EPS 1e-5f

namespace {

constexpr int Bb = 32;   // batch
constexpr int Cc = 512;  // channels
constexpr int Nn = 1024; // spatial (H*W)
constexpr int Ee = 1024; // embed

typedef __attribute__((ext_vector_type(8))) short short8;
typedef __attribute__((ext_vector_type(4))) float f32x4;
typedef __attribute__((ext_vector_type(4))) unsigned short ushort4_t;

struct bfpair { unsigned short h, l; };

__device__ __forceinline__ unsigned short bf16_rne(float v) {
  unsigned u = __builtin_bit_cast(unsigned, v);
  unsigned r = u + 0x7FFFu + ((u >> 16) & 1u);
  return (unsigned short)(r >> 16);
}
__device__ __forceinline__ float bf16_to_f(unsigned short h) {
  unsigned u = ((unsigned)h) << 16;
  return __builtin_bit_cast(float, u);
}
__device__ __forceinline__ bfpair split_bf(float v) {
  bfpair p;
  p.h = bf16_rne(v);
  p.l = bf16_rne(v - bf16_to_f(p.h));
  return p;
}

__device__ __forceinline__ void gll16(const void* g, void* l) {
  __builtin_amdgcn_global_load_lds(
      (const __attribute__((address_space(1))) void*)g,
      (__attribute__((address_space(3))) void*)l, 16, 0, 0);
}

// all three BN scale/shift pairs in one launch
__global__ __launch_bounds__(256) void prep3(
    const float* __restrict__ qg, const float* __restrict__ qb,
    const float* __restrict__ qm, const float* __restrict__ qv,
    const float* __restrict__ kg, const float* __restrict__ kb,
    const float* __restrict__ km, const float* __restrict__ kv,
    const float* __restrict__ vg, const float* __restrict__ vb,
    const float* __restrict__ vm, const float* __restrict__ vv,
    float* __restrict__ hdr) {
  int i = blockIdx.x * blockDim.x + threadIdx.x;
  if (i < 1024) {
    float inv, sc;
    inv = rsqrtf(qv[i] + BN_EPS); sc = qg[i] * inv;
    hdr[i] = sc;          hdr[1024 + i] = qb[i] - qm[i] * sc;
    inv = rsqrtf(kv[i] + BN_EPS); sc = kg[i] * inv;
    hdr[2048 + i] = sc;   hdr[3072 + i] = kb[i] - km[i] * sc;
    inv = rsqrtf(vv[i] + BN_EPS); sc = vg[i] * inv;
    hdr[4096 + i] = sc;   hdr[5120 + i] = vb[i] - vm[i] * sc;
  }
}

// plain f32 -> hi/lo bf16 split (weights)
__global__ __launch_bounds__(256) void convert_w(
    const float* __restrict__ wsrc, unsigned short* __restrict__ wh,
    unsigned short* __restrict__ wl, long total4) {
  for (long i = (long)blockIdx.x * 256 + threadIdx.x; i < total4; i += (long)gridDim.x * 256) {
    float4 v = ((const float4*)wsrc)[i];
    bfpair p0 = split_bf(v.x), p1 = split_bf(v.y), p2 = split_bf(v.z), p3 = split_bf(v.w);
    ushort4_t hv, lv;
    hv.x = p0.h; hv.y = p1.h; hv.z = p2.h; hv.w = p3.h;
    lv.x = p0.l; lv.y = p1.l; lv.z = p2.l; lv.w = p3.l;
    *(ushort4_t*)&wh[i * 4] = hv;
    *(ushort4_t*)&wl[i * 4] = lv;
  }
}

// ---------------------------------------------------------------------------
// Shared GEMM core notes:
// LDS tiles [128][32] ushort with chunk-XOR swizzle: LDS[row][c] holds global
// chunk c ^ ((row>>1)&3) (chunk = 8 elements). gll16 side achieves this by
// permuting the global source column; reg-staged side writes swizzled directly.
// Fragment reads use kq = ((lane>>4) ^ ((fr>>1)&3))*8 -> conflict-free (r5: 0).
// C/D layout col = lane&15, row = (lane>>4)*4 + reg [verified m89/m91].
// ---------------------------------------------------------------------------

// Projection GEMM with BN+ReLU fused on the f32 x operand (reg-staged).
// C[m][n] = sum_k A[m][k]*B[n][k]; K = 1024 fixed.
// BN_ON_A: A = BN(x) (Vt GEMM), B = W. else: A = W (stacked Wq;Wk), B = BN(x),
//          with BN params selected by m0 (m0 < 1024 -> q, else k).
// MFIRST: fastest grid index is m (groups m-tiles sharing the x panel).
template<bool BN_ON_A, bool MFIRST>
__global__ __launch_bounds__(256) void gemm_bn(
    const unsigned short* __restrict__ Wh, const unsigned short* __restrict__ Wl,
    const float* __restrict__ X, long bsX,
    const float* __restrict__ s0, const float* __restrict__ t0,
    const float* __restrict__ s1, const float* __restrict__ t1,
    unsigned short* __restrict__ Chi, unsigned short* __restrict__ Clo,
    long ldC, long bsC, int g0, int g1) {
  constexpr int K = 1024;
  __shared__ unsigned short sWh[128][32], sWl[128][32], sXh[128][32], sXl[128][32];

  const int nb = gridDim.x;
  int f = blockIdx.x;
  if ((nb & 7) == 0) f = (f & 7) * (nb >> 3) + (f >> 3);  // XCD-chunked swizzle
  const int i0 = f % g0, i1 = (f / g0) % g1;
  const long zb = f / (g0 * g1);
  const int m0 = (MFIRST ? i0 : i1) * 128;
  const int n0 = (MFIRST ? i1 : i0) * 128;

  const int t = threadIdx.x, lane = t & 63, w = t >> 6;
  const int sr  = lane >> 2;
  const int skc = (((lane & 3) ^ ((lane >> 3) & 3)) * 8);      // permuted global col
  const int wr = w >> 1, wc = w & 1;
  const int fr = lane & 15;
  const int kq = ((((lane >> 4) & 3) ^ ((fr >> 1) & 3)) * 8);  // swizzled read col

  const float* sb = s0;
  const float* tb = t0;
  if (!BN_ON_A && m0 >= 1024) { sb = s1; tb = t1; }

  const int wrow0 = BN_ON_A ? n0 : m0;
  const unsigned short* w0 = Wh + (long)(wrow0 + w * 32 + sr) * K + skc;
  const unsigned short* w1 = Wl + (long)(wrow0 + w * 32 + sr) * K + skc;
  const long w16 = 16L * K;

  const int xrow0 = BN_ON_A ? m0 : n0;
  const int xr = t >> 1, xh = t & 1;  // staging row 0..127, k-half (16 elements)
  const float* xp = X + zb * bsX + (long)(xrow0 + xr) * Nn + xh * 16;
  const int swzr = (xr >> 1) & 3;

  typedef unsigned short (*tile_t)[32];
  tile_t pA0 = BN_ON_A ? sXh : sWh;
  tile_t pA1 = BN_ON_A ? sXl : sWl;
  tile_t pB0 = BN_ON_A ? sWh : sXh;
  tile_t pB1 = BN_ON_A ? sWl : sXl;

  f32x4 acc[4][4] = {};

  for (int k0 = 0; k0 < K; k0 += 32) {
    // issue x loads early (regs only; previous tile still being consumed)
    float4 xv[4];
#pragma unroll
    for (int j = 0; j < 4; ++j) xv[j] = *(const float4*)(xp + k0 + 4 * j);

    __syncthreads();  // previous tile fully consumed
    gll16(w0, &sWh[w * 32][0]);  gll16(w0 + w16, &sWh[w * 32 + 16][0]);
    gll16(w1, &sWl[w * 32][0]);  gll16(w1 + w16, &sWl[w * 32 + 16][0]);
    w0 += 32; w1 += 32;

    const int kbase = k0 + xh * 16;
#pragma unroll
    for (int cc = 0; cc < 2; ++cc) {  // two 8-element chunks per thread
      short8 hv, lv;
#pragma unroll
      for (int j = 0; j < 2; ++j) {
        float4 v  = xv[cc * 2 + j];
        float4 s4 = *(const float4*)(sb + kbase + cc * 8 + j * 4);
        float4 t4 = *(const float4*)(tb + kbase + cc * 8 + j * 4);
        bfpair p0 = split_bf(fmaxf(fmaf(v.x, s4.x, t4.x), 0.f));
        bfpair p1 = split_bf(fmaxf(fmaf(v.y, s4.y, t4.y), 0.f));
        bfpair p2 = split_bf(fmaxf(fmaf(v.z, s4.z, t4.z), 0.f));
        bfpair p3 = split_bf(fmaxf(fmaf(v.w, s4.w, t4.w), 0.f));
        hv[j * 4 + 0] = (short)p0.h; hv[j * 4 + 1] = (short)p1.h;
        hv[j * 4 + 2] = (short)p2.h; hv[j * 4 + 3] = (short)p3.h;
        lv[j * 4 + 0] = (short)p0.l; lv[j * 4 + 1] = (short)p1.l;
        lv[j * 4 + 2] = (short)p2.l; lv[j * 4 + 3] = (short)p3.l;
      }
      const int swc = (xh * 2 + cc) ^ swzr;
      *(short8*)&sXh[xr][swc * 8] = hv;
      *(short8*)&sXl[xr][swc * 8] = lv;
    }
    __syncthreads();  // tile ready

    short8 ah[4], al[4], bh[4], bl[4];
#pragma unroll
    for (int i = 0; i < 4; ++i) {
      ah[i] = *(const short8*)&pA0[wr * 64 + i * 16 + fr][kq];
      al[i] = *(const short8*)&pA1[wr * 64 + i * 16 + fr][kq];
      bh[i] = *(const short8*)&pB0[wc * 64 + i * 16 + fr][kq];
      bl[i] = *(const short8*)&pB1[wc * 64 + i * 16 + fr][kq];
    }
#pragma unroll
    for (int i = 0; i < 4; ++i)
#pragma unroll
      for (int j = 0; j < 4; ++j) {
        acc[i][j] = __builtin_amdgcn_mfma_f32_16x16x32_bf16(ah[i], bh[j], acc[i][j], 0, 0, 0);
        acc[i][j] = __builtin_amdgcn_mfma_f32_16x16x32_bf16(ah[i], bl[j], acc[i][j], 0, 0, 0);
        acc[i][j] = __builtin_amdgcn_mfma_f32_16x16x32_bf16(al[i], bh[j], acc[i][j], 0, 0, 0);
      }
  }

  const int rb = ((lane >> 4) & 3) * 4;
#pragma unroll
  for (int i = 0; i < 4; ++i)
#pragma unroll
    for (int j = 0; j < 4; ++j) {
      long col = n0 + wc * 64 + j * 16 + fr;
#pragma unroll
      for (int v = 0; v < 4; ++v) {
        long row = m0 + wr * 64 + i * 16 + rb + v;
        long idx = zb * bsC + row * ldC + col;
        bfpair p = split_bf(acc[i][j][v]);
        Chi[idx] = p.h;
        Clo[idx] = p.l;
      }
    }
}

// Split-bf16 NT GEMM, both operands bf16 hi/lo via gll16 (validated r5, 0 conflicts).
template<bool SPLIT>
__global__ __launch_bounds__(256) void gemm3(
    const unsigned short* __restrict__ Ah, const unsigned short* __restrict__ Al,
    long ldA, long bsA,
    const unsigned short* __restrict__ Bh, const unsigned short* __restrict__ Bl,
    long ldB, long bsB,
    float* __restrict__ Cf, unsigned short* __restrict__ Chi, unsigned short* __restrict__ Clo,
    long ldC, long bsC, int K, float alpha, int gx, int gy) {
  __shared__ unsigned short sAh[128][32], sAl[128][32], sBh[128][32], sBl[128][32];

  const int nb = gridDim.x;
  int f = blockIdx.x;
  if ((nb & 7) == 0) f = (f & 7) * (nb >> 3) + (f >> 3);
  const int n0 = (f % gx) * 128;
  const int m0 = ((f / gx) % gy) * 128;
  const long zb = f / (gx * gy);

  const int t = threadIdx.x, lane = t & 63, w = t >> 6;
  const int sr  = lane >> 2;
  const int skc = (((lane & 3) ^ ((lane >> 3) & 3)) * 8);
  const int wr = w >> 1, wc = w & 1;
  const int fr = lane & 15;
  const int kq = ((((lane >> 4) & 3) ^ ((fr >> 1) & 3)) * 8);

  const unsigned short* a0 = Ah + zb * bsA + (long)(m0 + w * 32 + sr) * ldA + skc;
  const unsigned short* a1 = Al + zb * bsA + (long)(m0 + w * 32 + sr) * ldA + skc;
  const unsigned short* b0 = Bh + zb * bsB + (long)(n0 + w * 32 + sr) * ldB + skc;
  const unsigned short* b1 = Bl + zb * bsB + (long)(n0 + w * 32 + sr) * ldB + skc;
  const long a16 = 16 * ldA, b16 = 16 * ldB;

  f32x4 acc[4][4] = {};

  for (int k0 = 0; k0 < K; k0 += 32) {
    __syncthreads();
    gll16(a0, &sAh[w * 32][0]);      gll16(a0 + a16, &sAh[w * 32 + 16][0]);
    gll16(a1, &sAl[w * 32][0]);      gll16(a1 + a16, &sAl[w * 32 + 16][0]);
    gll16(b0, &sBh[w * 32][0]);      gll16(b0 + b16, &sBh[w * 32 + 16][0]);
    gll16(b1, &sBl[w * 32][0]);      gll16(b1 + b16, &sBl[w * 32 + 16][0]);
    a0 += 32; a1 += 32; b0 += 32; b1 += 32;
    __syncthreads();

    short8 ah[4], al[4], bh[4], bl[4];
#pragma unroll
    for (int i = 0; i < 4; ++i) {
      ah[i] = *(const short8*)&sAh[wr * 64 + i * 16 + fr][kq];
      al[i] = *(const short8*)&sAl[wr * 64 + i * 16 + fr][kq];
      bh[i] = *(const short8*)&sBh[wc * 64 + i * 16 + fr][kq];
      bl[i] = *(const short8*)&sBl[wc * 64 + i * 16 + fr][kq];
    }
#pragma unroll
    for (int i = 0; i < 4; ++i)
#pragma unroll
      for (int j = 0; j < 4; ++j) {
        acc[i][j] = __builtin_amdgcn_mfma_f32_16x16x32_bf16(ah[i], bh[j], acc[i][j], 0, 0, 0);
        acc[i][j] = __builtin_amdgcn_mfma_f32_16x16x32_bf16(ah[i], bl[j], acc[i][j], 0, 0, 0);
        acc[i][j] = __builtin_amdgcn_mfma_f32_16x16x32_bf16(al[i], bh[j], acc[i][j], 0, 0, 0);
      }
  }

  const int rb = ((lane >> 4) & 3) * 4;
#pragma unroll
  for (int i = 0; i < 4; ++i)
#pragma unroll
    for (int j = 0; j < 4; ++j) {
      long col = n0 + wc * 64 + j * 16 + fr;
#pragma unroll
      for (int v = 0; v < 4; ++v) {
        long row = m0 + wr * 64 + i * 16 + rb + v;
        float val = acc[i][j][v] * alpha;
        long idx = zb * bsC + row * ldC + col;
        if (SPLIT) {
          bfpair p = split_bf(val);
          Chi[idx] = p.h;
          Clo[idx] = p.l;
        } else {
          Cf[idx] = val;
        }
      }
    }
}

// softmax over rows of 1024 f32, writes P split as hi[1024]|lo[1024] ushorts in place.
__global__ __launch_bounds__(256) void softmax_rows(float* __restrict__ S) {
  long row = blockIdx.x;
  float* p = S + row * 1024;
  int t = threadIdx.x;
  float4 v = *(float4*)(p + 4 * t);
  float mx = fmaxf(fmaxf(v.x, v.y), fmaxf(v.z, v.w));
#pragma unroll
  for (int i = 1; i < 64; i <<= 1) mx = fmaxf(mx, __shfl_xor(mx, i));
  __shared__ float redm[4];
  __shared__ float reds[4];
  int wave = t >> 6, lane = t & 63;
  if (lane == 0) redm[wave] = mx;
  __syncthreads();
  mx = fmaxf(fmaxf(redm[0], redm[1]), fmaxf(redm[2], redm[3]));
  float e0 = expf(v.x - mx), e1 = expf(v.y - mx);
  float e2 = expf(v.z - mx), e3 = expf(v.w - mx);
  float sum = (e0 + e1) + (e2 + e3);
#pragma unroll
  for (int i = 1; i < 64; i <<= 1) sum += __shfl_xor(sum, i);
  if (lane == 0) reds[wave] = sum;
  __syncthreads();
  sum = (reds[0] + reds[1]) + (reds[2] + reds[3]);
  float inv = 1.0f / sum;
  bfpair p0 = split_bf(e0 * inv), p1 = split_bf(e1 * inv);
  bfpair p2 = split_bf(e2 * inv), p3 = split_bf(e3 * inv);
  ushort4_t hv, lv;
  hv.x = p0.h; hv.y = p1.h; hv.z = p2.h; hv.w = p3.h;
  lv.x = p0.l; lv.y = p1.l; lv.z = p2.l; lv.w = p3.l;
  unsigned short* ph = (unsigned short*)p;
  *(ushort4_t*)&ph[4 * t] = hv;
  *(ushort4_t*)&ph[1024 + 4 * t] = lv;
}

}  // namespace

extern "C" void kernel_launch(void* const* d_in, const int* in_sizes, int n_in,
                              void* d_out, int out_size, void* d_ws, size_t ws_size,
                              hipStream_t stream) {
  const float* x  = (const float*)d_in[0];
  const float* qg = (const float*)d_in[1];
  const float* qb = (const float*)d_in[2];
  const float* qm = (const float*)d_in[3];
  const float* qv = (const float*)d_in[4];
  const float* kg = (const float*)d_in[5];
  const float* kb = (const float*)d_in[6];
  const float* km = (const float*)d_in[7];
  const float* kv = (const float*)d_in[8];
  const float* vg = (const float*)d_in[9];
  const float* vb = (const float*)d_in[10];
  const float* vm = (const float*)d_in[11];
  const float* vv = (const float*)d_in[12];
  const float* Wq = (const float*)d_in[13];
  const float* Wk = (const float*)d_in[14];
  const float* Wv = (const float*)d_in[15];
  const float* Wp = (const float*)d_in[16];

  // ---- workspace ----
  // header 64 KiB | stacked WQK hi/lo 8 MiB | Wv hi/lo 4 | Wp hi/lo 4 |
  // per batch: QK-stacked C hi/lo 4 MiB (reused as Ot) + S 4 MiB = 8 MiB
  // Vt (hi|lo per batch) lives in d_out (consumed by PV before out overwrites).
  const size_t wFix = 65536 + 16UL * 1024 * 1024;
  const size_t perB = 8UL * 1024 * 1024;
  int G = 32;
  while (G > 1 && wFix + (size_t)G * perB > ws_size) G >>= 1;

  char* ws = (char*)d_ws;
  float* hdr = (float*)ws;
  float* sq = hdr;        float* tq = hdr + 1024;
  float* sk = hdr + 2048; float* tk = hdr + 3072;
  float* sv = hdr + 4096; float* tv = hdr + 5120;

  const long WE = 1024L * 1024;
  unsigned short* WQKh = (unsigned short*)(ws + 65536);  // [2048][1024]
  unsigned short* WQKl = WQKh + 2 * WE;
  unsigned short* Wvh  = WQKl + 2 * WE;
  unsigned short* Wvl  = Wvh + WE;
  unsigned short* Wph  = Wvl + WE;
  unsigned short* Wpl  = Wph + WE;

  const long QKBS = 2048L * 512;          // 1,048,576 elements/batch (hi or lo)
  unsigned short* QKh = Wpl + WE;
  unsigned short* QKl = QKh + (long)G * QKBS;
  float* S = (float*)(QKl + (long)G * QKBS);  // [G][1024][1024] f32

  unsigned short* Vth = (unsigned short*)d_out;  // [b]: hi 524288 | lo 524288
  const long VTBS = 1048576;

  dim3 blk(256);

  prep3<<<dim3(4), blk, 0, stream>>>(qg, qb, qm, qv, kg, kb, km, kv, vg, vb, vm, vv, hdr);

  const long W4 = WE / 4;
  convert_w<<<dim3(1024), blk, 0, stream>>>(Wq, WQKh, WQKl, W4);
  convert_w<<<dim3(1024), blk, 0, stream>>>(Wk, WQKh + WE, WQKl + WE, W4);
  convert_w<<<dim3(1024), blk, 0, stream>>>(Wv, Wvh, Wvl, W4);
  convert_w<<<dim3(1024), blk, 0, stream>>>(Wp, Wph, Wpl, W4);

  // ---- Vt for ALL batches: Vt[b,c,e] = sum_n BN_v(x[b,c,n]) * Wv[e,n] ----
  // BN on A side, n-fastest (x panel reuse). grid 8*4*32 = 1024 blocks.
  gemm_bn<true, false><<<dim3((Ee / 128) * (Cc / 128) * Bb), blk, 0, stream>>>(
      Wvh, Wvl, x, (long)Cc * Nn, sv, tv, nullptr, nullptr,
      Vth, Vth + 524288, Ee, VTBS, Ee / 128, Cc / 128);

  for (int b0 = 0; b0 < Bb; b0 += G) {
    const float* xg = x + (size_t)b0 * Cc * Nn;

    // ---- [Q;K] = [Wq;Wk] x BN(x): M=2048, N=C, K=Nn; m-fastest ----
    gemm_bn<false, true><<<dim3(16 * (Cc / 128) * G), blk, 0, stream>>>(
        WQKh, WQKl, xg, (long)Cc * Nn, sq, tq, sk, tk,
        QKh, QKl, Cc, QKBS, 16, Cc / 128);

    // ---- S = Q K^T / 32: M=E, N=E, K=C ----
    gemm3<false><<<dim3((Ee / 128) * (Ee / 128) * G), blk, 0, stream>>>(
        QKh, QKl, Cc, QKBS, QKh + 1024 * 512, QKl + 1024 * 512, Cc, QKBS,
        S, nullptr, nullptr, Ee, 1048576L, Cc, 0.03125f, Ee / 128, Ee / 128);

    // ---- softmax rows -> P hi/lo packed in S ----
    softmax_rows<<<dim3(G * Ee), blk, 0, stream>>>(S);

    // ---- Ot = Vt x P^T: M=C, N=E, K=E (Ot reuses QK region; Q,K dead) ----
    gemm3<true><<<dim3((Ee / 128) * (Cc / 128) * G), blk, 0, stream>>>(
        Vth + (long)b0 * VTBS, Vth + (long)b0 * VTBS + 524288, Ee, VTBS,
        (unsigned short*)S, (unsigned short*)S + 1024, 2L * Ee, 2097152L,
        nullptr, QKh, QKl, Ee, QKBS, Ee, 1.0f, Ee / 128, Cc / 128);

    // ---- out = Ot x Wp^T: M=C, N=Nn, K=E -> f32 d_out (overwrites Vt slots) ----
    gemm3<false><<<dim3((Nn / 128) * (Cc / 128) * G), blk, 0, stream>>>(
        QKh, QKl, Ee, QKBS, Wph, Wpl, Ee, 0L,
        (float*)d_out + (size_t)b0 * Cc * Nn, nullptr, nullptr,
        Nn, (long)Cc * Nn, Ee, 1.0f, Nn / 128, Cc / 128);
  }
}

// Round 7
// 755.268 us; speedup vs baseline: 1.5835x; 1.1301x over previous
//
#include <hip/hip_runtime.h>
#include <math.h>

#define BN_EPS 1e-5f

namespace {

constexpr int Bb = 32;   // batch
constexpr int Cc = 512;  // channels
constexpr int Nn = 1024; // spatial (H*W)
constexpr int Ee = 1024; // embed

typedef __attribute__((ext_vector_type(8))) short short8;
typedef __attribute__((ext_vector_type(4))) float f32x4;
typedef __attribute__((ext_vector_type(4))) unsigned short ushort4_t;

struct bfpair { unsigned short h, l; };

__device__ __forceinline__ unsigned short bf16_rne(float v) {
  unsigned u = __builtin_bit_cast(unsigned, v);
  unsigned r = u + 0x7FFFu + ((u >> 16) & 1u);
  return (unsigned short)(r >> 16);
}
__device__ __forceinline__ float bf16_to_f(unsigned short h) {
  unsigned u = ((unsigned)h) << 16;
  return __builtin_bit_cast(float, u);
}
__device__ __forceinline__ bfpair split_bf(float v) {
  bfpair p;
  p.h = bf16_rne(v);
  p.l = bf16_rne(v - bf16_to_f(p.h));
  return p;
}

__device__ __forceinline__ void gll16(const void* g, void* l) {
  __builtin_amdgcn_global_load_lds(
      (const __attribute__((address_space(1))) void*)g,
      (__attribute__((address_space(3))) void*)l, 16, 0, 0);
}

// all three BN scale/shift pairs in one launch -> hdr[6][1024]
__global__ __launch_bounds__(256) void prep3(
    const float* __restrict__ qg, const float* __restrict__ qb,
    const float* __restrict__ qm, const float* __restrict__ qv,
    const float* __restrict__ kg, const float* __restrict__ kb,
    const float* __restrict__ km, const float* __restrict__ kv,
    const float* __restrict__ vg, const float* __restrict__ vb,
    const float* __restrict__ vm, const float* __restrict__ vv,
    float* __restrict__ hdr) {
  int i = blockIdx.x * blockDim.x + threadIdx.x;
  if (i < 1024) {
    float inv, sc;
    inv = rsqrtf(qv[i] + BN_EPS); sc = qg[i] * inv;
    hdr[i] = sc;          hdr[1024 + i] = qb[i] - qm[i] * sc;
    inv = rsqrtf(kv[i] + BN_EPS); sc = kg[i] * inv;
    hdr[2048 + i] = sc;   hdr[3072 + i] = kb[i] - km[i] * sc;
    inv = rsqrtf(vv[i] + BN_EPS); sc = vg[i] * inv;
    hdr[4096 + i] = sc;   hdr[5120 + i] = vb[i] - vm[i] * sc;
  }
}

// plain f32 -> hi/lo bf16 split (weights)
__global__ __launch_bounds__(256) void convert_w(
    const float* __restrict__ wsrc, unsigned short* __restrict__ wh,
    unsigned short* __restrict__ wl, long total4) {
  for (long i = (long)blockIdx.x * 256 + threadIdx.x; i < total4; i += (long)gridDim.x * 256) {
    float4 v = ((const float4*)wsrc)[i];
    bfpair p0 = split_bf(v.x), p1 = split_bf(v.y), p2 = split_bf(v.z), p3 = split_bf(v.w);
    ushort4_t hv, lv;
    hv.x = p0.h; hv.y = p1.h; hv.z = p2.h; hv.w = p3.h;
    lv.x = p0.l; lv.y = p1.l; lv.z = p2.l; lv.w = p3.l;
    *(ushort4_t*)&wh[i * 4] = hv;
    *(ushort4_t*)&wl[i * 4] = lv;
  }
}

// One x pass -> yq, yk (ws) and yv (d_out batch slots), all split hi/lo bf16.
// x flat [G][C][N]; 131072 float4 per batch.
__global__ __launch_bounds__(256) void convert_y3(
    const float* __restrict__ x, const float* __restrict__ hdr,
    unsigned short* __restrict__ yqh, unsigned short* __restrict__ yql,
    unsigned short* __restrict__ ykh, unsigned short* __restrict__ ykl,
    unsigned short* __restrict__ dout_us, long b0, long total4) {
  const float* sq = hdr;        const float* tq = hdr + 1024;
  const float* sk = hdr + 2048; const float* tk = hdr + 3072;
  const float* sv = hdr + 4096; const float* tv = hdr + 5120;
  for (long i = (long)blockIdx.x * 256 + threadIdx.x; i < total4; i += (long)gridDim.x * 256) {
    float4 v = ((const float4*)x)[i];
    int n4 = (int)(i & 255);
    float4 a, b;
    ushort4_t hv, lv;
    // q
    a = ((const float4*)sq)[n4]; b = ((const float4*)tq)[n4];
    {
      bfpair p0 = split_bf(fmaxf(fmaf(v.x, a.x, b.x), 0.f));
      bfpair p1 = split_bf(fmaxf(fmaf(v.y, a.y, b.y), 0.f));
      bfpair p2 = split_bf(fmaxf(fmaf(v.z, a.z, b.z), 0.f));
      bfpair p3 = split_bf(fmaxf(fmaf(v.w, a.w, b.w), 0.f));
      hv.x = p0.h; hv.y = p1.h; hv.z = p2.h; hv.w = p3.h;
      lv.x = p0.l; lv.y = p1.l; lv.z = p2.l; lv.w = p3.l;
      *(ushort4_t*)&yqh[i * 4] = hv; *(ushort4_t*)&yql[i * 4] = lv;
    }
    // k
    a = ((const float4*)sk)[n4]; b = ((const float4*)tk)[n4];
    {
      bfpair p0 = split_bf(fmaxf(fmaf(v.x, a.x, b.x), 0.f));
      bfpair p1 = split_bf(fmaxf(fmaf(v.y, a.y, b.y), 0.f));
      bfpair p2 = split_bf(fmaxf(fmaf(v.z, a.z, b.z), 0.f));
      bfpair p3 = split_bf(fmaxf(fmaf(v.w, a.w, b.w), 0.f));
      hv.x = p0.h; hv.y = p1.h; hv.z = p2.h; hv.w = p3.h;
      lv.x = p0.l; lv.y = p1.l; lv.z = p2.l; lv.w = p3.l;
      *(ushort4_t*)&ykh[i * 4] = hv; *(ushort4_t*)&ykl[i * 4] = lv;
    }
    // v -> d_out slot (b0+g): hi[524288] | lo[524288]
    a = ((const float4*)sv)[n4]; b = ((const float4*)tv)[n4];
    {
      bfpair p0 = split_bf(fmaxf(fmaf(v.x, a.x, b.x), 0.f));
      bfpair p1 = split_bf(fmaxf(fmaf(v.y, a.y, b.y), 0.f));
      bfpair p2 = split_bf(fmaxf(fmaf(v.z, a.z, b.z), 0.f));
      bfpair p3 = split_bf(fmaxf(fmaf(v.w, a.w, b.w), 0.f));
      hv.x = p0.h; hv.y = p1.h; hv.z = p2.h; hv.w = p3.h;
      lv.x = p0.l; lv.y = p1.l; lv.z = p2.l; lv.w = p3.l;
      long g = i >> 17;           // batch within chunk
      long local = i & 131071;
      unsigned short* slot = dout_us + (b0 + g) * 1048576L;
      *(ushort4_t*)&slot[local * 4] = hv;
      *(ushort4_t*)&slot[524288 + local * 4] = lv;
    }
  }
}

// ---------------------------------------------------------------------------
// Pipelined split-bf16 NT GEMM: C[m][n] = alpha * sum_k A[m][k]*B[n][k].
// 128x128 tile, BK=32, 4 waves (2x2 of 64x64), mfma 16x16x32 bf16,
// acc += Ah*Bh + Ah*Bl + Al*Bh.
// LDS: DOUBLE-buffered [2] x {A hi/lo, B hi/lo} x [128][32] = 64 KiB.
// Pipeline (T3/T4): 2-deep gll16 prefetch; per iter: vmcnt(8) counted wait
// (next tile's 8 loads stay in flight) -> barrier -> frag ds_reads ->
// lgkmcnt(0) -> barrier -> STAGE(t+2) -> setprio(1) MFMA x48 setprio(0).
// Chunk-XOR swizzle as validated (r5/r6: 0 conflicts).
// B operand selected by m0 (>= msel -> B1) for stacked-[Wq;Wk] projection.
// ---------------------------------------------------------------------------
template<bool SPLIT, bool MFIRST>
__global__ __launch_bounds__(256, 2) void gemm3p(
    const unsigned short* __restrict__ Ah, const unsigned short* __restrict__ Al,
    long ldA, long bsA,
    const unsigned short* __restrict__ Bh0, const unsigned short* __restrict__ Bl0,
    const unsigned short* __restrict__ Bh1, const unsigned short* __restrict__ Bl1,
    int msel, long ldB, long bsB,
    float* __restrict__ Cf, unsigned short* __restrict__ Chi, unsigned short* __restrict__ Clo,
    long ldC, long bsC, int K, float alpha, int g0, int g1) {
  __shared__ unsigned short sA[2][2][128][32];
  __shared__ unsigned short sB[2][2][128][32];

  const int nb = gridDim.x;
  int f = blockIdx.x;
  if ((nb & 7) == 0) f = (f & 7) * (nb >> 3) + (f >> 3);  // XCD-chunked swizzle
  const int i0 = f % g0, i1 = (f / g0) % g1;
  const long zb = f / (g0 * g1);
  const int m0 = (MFIRST ? i0 : i1) * 128;
  const int n0 = (MFIRST ? i1 : i0) * 128;

  const int t = threadIdx.x, lane = t & 63, w = t >> 6;
  const int sr  = lane >> 2;
  const int skc = (((lane & 3) ^ ((lane >> 3) & 3)) * 8);      // permuted global col
  const int wr = w >> 1, wc = w & 1;
  const int fr = lane & 15;
  const int kq = ((((lane >> 4) & 3) ^ ((fr >> 1) & 3)) * 8);  // swizzled read col

  const unsigned short* Bh = (m0 >= msel) ? Bh1 : Bh0;
  const unsigned short* Bl = (m0 >= msel) ? Bl1 : Bl0;

  const unsigned short* a0 = Ah + zb * bsA + (long)(m0 + w * 32 + sr) * ldA + skc;
  const unsigned short* a1 = Al + zb * bsA + (long)(m0 + w * 32 + sr) * ldA + skc;
  const unsigned short* b0 = Bh + zb * bsB + (long)(n0 + w * 32 + sr) * ldB + skc;
  const unsigned short* b1 = Bl + zb * bsB + (long)(n0 + w * 32 + sr) * ldB + skc;
  const long a16 = 16 * ldA, b16 = 16 * ldB;

  // per-thread loads per STAGE = 8  (vmcnt counting depends on this)
  auto STAGE = [&](int buf) {
    gll16(a0, &sA[buf][0][w * 32][0]);  gll16(a0 + a16, &sA[buf][0][w * 32 + 16][0]);
    gll16(a1, &sA[buf][1][w * 32][0]);  gll16(a1 + a16, &sA[buf][1][w * 32 + 16][0]);
    gll16(b0, &sB[buf][0][w * 32][0]);  gll16(b0 + b16, &sB[buf][0][w * 32 + 16][0]);
    gll16(b1, &sB[buf][1][w * 32][0]);  gll16(b1 + b16, &sB[buf][1][w * 32 + 16][0]);
    a0 += 32; a1 += 32; b0 += 32; b1 += 32;
  };

  f32x4 acc[4][4] = {};
  const int nt = K >> 5;

  STAGE(0);
  STAGE(1);
  int cur = 0;

  for (int it = 0; it < nt; ++it) {
    if (it + 1 < nt) asm volatile("s_waitcnt vmcnt(8)" ::: "memory");
    else             asm volatile("s_waitcnt vmcnt(0)" ::: "memory");
    asm volatile("s_barrier" ::: "memory");   // buf[cur] staged by all waves

    short8 ah[4], al[4], bh[4], bl[4];
#pragma unroll
    for (int i = 0; i < 4; ++i) {
      ah[i] = *(const short8*)&sA[cur][0][wr * 64 + i * 16 + fr][kq];
      al[i] = *(const short8*)&sA[cur][1][wr * 64 + i * 16 + fr][kq];
      bh[i] = *(const short8*)&sB[cur][0][wc * 64 + i * 16 + fr][kq];
      bl[i] = *(const short8*)&sB[cur][1][wc * 64 + i * 16 + fr][kq];
    }
    asm volatile("s_waitcnt lgkmcnt(0)" ::: "memory");  // my reads complete
    asm volatile("s_barrier" ::: "memory");             // all waves' reads done
    if (it + 2 < nt) STAGE(cur);                        // overwrite safe now

    __builtin_amdgcn_s_setprio(1);
#pragma unroll
    for (int i = 0; i < 4; ++i)
#pragma unroll
      for (int j = 0; j < 4; ++j) {
        acc[i][j] = __builtin_amdgcn_mfma_f32_16x16x32_bf16(ah[i], bh[j], acc[i][j], 0, 0, 0);
        acc[i][j] = __builtin_amdgcn_mfma_f32_16x16x32_bf16(ah[i], bl[j], acc[i][j], 0, 0, 0);
        acc[i][j] = __builtin_amdgcn_mfma_f32_16x16x32_bf16(al[i], bh[j], acc[i][j], 0, 0, 0);
      }
    __builtin_amdgcn_s_setprio(0);
    cur ^= 1;
  }

  // epilogue: C/D layout col = lane&15, row = (lane>>4)*4 + reg  [verified m89/m91]
  const int rb = ((lane >> 4) & 3) * 4;
#pragma unroll
  for (int i = 0; i < 4; ++i)
#pragma unroll
    for (int j = 0; j < 4; ++j) {
      long col = n0 + wc * 64 + j * 16 + fr;
#pragma unroll
      for (int v = 0; v < 4; ++v) {
        long row = m0 + wr * 64 + i * 16 + rb + v;
        float val = acc[i][j][v] * alpha;
        long idx = zb * bsC + row * ldC + col;
        if (SPLIT) {
          bfpair p = split_bf(val);
          Chi[idx] = p.h;
          Clo[idx] = p.l;
        } else {
          Cf[idx] = val;
        }
      }
    }
}

// softmax over rows of 1024 f32, writes P split as hi[1024]|lo[1024] ushorts in place.
__global__ __launch_bounds__(256) void softmax_rows(float* __restrict__ S) {
  long row = blockIdx.x;
  float* p = S + row * 1024;
  int t = threadIdx.x;
  float4 v = *(float4*)(p + 4 * t);
  float mx = fmaxf(fmaxf(v.x, v.y), fmaxf(v.z, v.w));
#pragma unroll
  for (int i = 1; i < 64; i <<= 1) mx = fmaxf(mx, __shfl_xor(mx, i));
  __shared__ float redm[4];
  __shared__ float reds[4];
  int wave = t >> 6, lane = t & 63;
  if (lane == 0) redm[wave] = mx;
  __syncthreads();
  mx = fmaxf(fmaxf(redm[0], redm[1]), fmaxf(redm[2], redm[3]));
  float e0 = expf(v.x - mx), e1 = expf(v.y - mx);
  float e2 = expf(v.z - mx), e3 = expf(v.w - mx);
  float sum = (e0 + e1) + (e2 + e3);
#pragma unroll
  for (int i = 1; i < 64; i <<= 1) sum += __shfl_xor(sum, i);
  if (lane == 0) reds[wave] = sum;
  __syncthreads();
  sum = (reds[0] + reds[1]) + (reds[2] + reds[3]);
  float inv = 1.0f / sum;
  bfpair p0 = split_bf(e0 * inv), p1 = split_bf(e1 * inv);
  bfpair p2 = split_bf(e2 * inv), p3 = split_bf(e3 * inv);
  ushort4_t hv, lv;
  hv.x = p0.h; hv.y = p1.h; hv.z = p2.h; hv.w = p3.h;
  lv.x = p0.l; lv.y = p1.l; lv.z = p2.l; lv.w = p3.l;
  unsigned short* ph = (unsigned short*)p;
  *(ushort4_t*)&ph[4 * t] = hv;
  *(ushort4_t*)&ph[1024 + 4 * t] = lv;
}

}  // namespace

extern "C" void kernel_launch(void* const* d_in, const int* in_sizes, int n_in,
                              void* d_out, int out_size, void* d_ws, size_t ws_size,
                              hipStream_t stream) {
  const float* x  = (const float*)d_in[0];
  const float* qg = (const float*)d_in[1];
  const float* qb = (const float*)d_in[2];
  const float* qm = (const float*)d_in[3];
  const float* qv = (const float*)d_in[4];
  const float* kg = (const float*)d_in[5];
  const float* kb = (const float*)d_in[6];
  const float* km = (const float*)d_in[7];
  const float* kv = (const float*)d_in[8];
  const float* vg = (const float*)d_in[9];
  const float* vb = (const float*)d_in[10];
  const float* vm = (const float*)d_in[11];
  const float* vv = (const float*)d_in[12];
  const float* Wq = (const float*)d_in[13];
  const float* Wk = (const float*)d_in[14];
  const float* Wv = (const float*)d_in[15];
  const float* Wp = (const float*)d_in[16];

  // ---- workspace ----
  // fixed: hdr 64 KiB | WQK hi/lo 8 MiB | Wv hi/lo 4 | Wp hi/lo 4  = ~16 MiB
  // per batch: yq+yk hi/lo 4 MiB | QK hi/lo 4 MiB | S 4 MiB        = 12 MiB
  // yv hi/lo lives in the batch's d_out slot (2 MiB); Vt overwrites yq/yk;
  // Ot overwrites QK; out overwrites the d_out slot.  G=16 -> 208 MiB.
  const size_t wFix = 65536 + 16UL * 1024 * 1024;
  const size_t perB = 12UL * 1024 * 1024;
  int G = 32;
  while (G > 1 && wFix + (size_t)G * perB > ws_size) G >>= 1;

  char* ws = (char*)d_ws;
  float* hdr = (float*)ws;

  const long WE = 1024L * 1024;
  unsigned short* WQKh = (unsigned short*)(ws + 65536);  // [2048][1024]
  unsigned short* WQKl = WQKh + 2 * WE;
  unsigned short* Wvh  = WQKl + 2 * WE;
  unsigned short* Wvl  = Wvh + WE;
  unsigned short* Wph  = Wvl + WE;
  unsigned short* Wpl  = Wph + WE;

  const long YB = 524288;  // elements/batch of y arrays ([C][N])
  unsigned short* yqh = Wpl + WE;
  unsigned short* yql = yqh + (long)G * YB;
  unsigned short* ykh = yql + (long)G * YB;
  unsigned short* ykl = ykh + (long)G * YB;
  const long QKBS = 1048576;  // [2048][512] per batch
  unsigned short* QKh = ykl + (long)G * YB;
  unsigned short* QKl = QKh + (long)G * QKBS;
  float* S = (float*)(QKl + (long)G * QKBS);  // [G][1024][1024]

  unsigned short* dout_us = (unsigned short*)d_out;  // per batch: yv hi|lo slot

  dim3 blk(256);
  const int BIG = 1 << 30;

  prep3<<<dim3(4), blk, 0, stream>>>(qg, qb, qm, qv, kg, kb, km, kv, vg, vb, vm, vv, hdr);

  const long W4 = WE / 4;
  convert_w<<<dim3(1024), blk, 0, stream>>>(Wq, WQKh, WQKl, W4);
  convert_w<<<dim3(1024), blk, 0, stream>>>(Wk, WQKh + WE, WQKl + WE, W4);
  convert_w<<<dim3(1024), blk, 0, stream>>>(Wv, Wvh, Wvl, W4);
  convert_w<<<dim3(1024), blk, 0, stream>>>(Wp, Wph, Wpl, W4);

  for (int b0 = 0; b0 < Bb; b0 += G) {
    const float* xg = x + (size_t)b0 * Cc * Nn;

    // 1) BN+ReLU+split: yq,yk -> ws; yv -> d_out slots
    convert_y3<<<dim3(2048), blk, 0, stream>>>(
        xg, hdr, yqh, yql, ykh, ykl, dout_us, b0, (long)G * 131072);

    // 2) [Q;K] = [Wq;Wk] x y: M=2048 (B = yq for m<1024, yk above), N=C, K=Nn
    gemm3p<true, true><<<dim3(16 * 4 * G), blk, 0, stream>>>(
        WQKh, WQKl, Nn, 0L,
        yqh, yql, ykh, ykl, 1024, Nn, YB,
        nullptr, QKh, QKl, Cc, QKBS, Nn, 1.0f, 16, 4);

    // 3) S = Q K^T / 32: M=E, N=E, K=C
    gemm3p<false, false><<<dim3(8 * 8 * G), blk, 0, stream>>>(
        QKh, QKl, Cc, QKBS,
        QKh + 524288, QKl + 524288, nullptr, nullptr, BIG, Cc, QKBS,
        S, nullptr, nullptr, Ee, 1048576L, Cc, 0.03125f, 8, 8);

    // 4) softmax rows -> P hi/lo packed in S
    softmax_rows<<<dim3(G * Ee), blk, 0, stream>>>(S);

    // 5) Vt[c][e] = sum_n yv[c][n] Wv[e][n]: A = yv (d_out slots), out -> yq/yk region
    gemm3p<true, false><<<dim3(8 * 4 * G), blk, 0, stream>>>(
        dout_us + (long)b0 * 1048576, dout_us + (long)b0 * 1048576 + 524288, Nn, 1048576L,
        Wvh, Wvl, nullptr, nullptr, BIG, Nn, 0L,
        nullptr, yqh, yql, Ee, YB, Nn, 1.0f, 8, 4);

    // 6) Ot[c][e] = sum_f Vt[c][f] P[e][f]: B = P in S (ld 2048), out -> QK region
    gemm3p<true, false><<<dim3(8 * 4 * G), blk, 0, stream>>>(
        yqh, yql, Ee, YB,
        (unsigned short*)S, (unsigned short*)S + 1024, nullptr, nullptr, BIG,
        2L * Ee, 2097152L,
        nullptr, QKh, QKl, Ee, QKBS, Ee, 1.0f, 8, 4);

    // 7) out[c][n] = sum_e Ot[c][e] Wp[n][e]: f32 -> d_out slot (yv dead)
    gemm3p<false, false><<<dim3(8 * 4 * G), blk, 0, stream>>>(
        QKh, QKl, Ee, QKBS,
        Wph, Wpl, nullptr, nullptr, BIG, Ee, 0L,
        (float*)d_out + (size_t)b0 * Cc * Nn, nullptr, nullptr,
        Nn, (long)Cc * Nn, Ee, 1.0f, 8, 4);
  }
}